// Round 6
// baseline (405.890 us; speedup 1.0000x reference)
//
#include <hip/hip_runtime.h>
#include <math.h>

#define N_OUT 32
#define D_OUT 32
#define N_IN 2048
#define D_IN 16
#define BATCH 64
#define J 1024           // N_OUT*D_OUT

typedef __attribute__((ext_vector_type(8))) short short8;   // 8 bf16 (4 VGPR)
typedef __attribute__((ext_vector_type(4))) float f32x4;    // MFMA C/D

// f32 -> bf16 RNE
__device__ __forceinline__ unsigned short f2bf(float f) {
  unsigned int x = __float_as_uint(f);
  unsigned int r = (x + 0x7FFFu + ((x >> 16) & 1u)) >> 16;
  return (unsigned short)r;
}

// 16B-unit swizzle inside one n-tile (2048 units): XOR bit0 with bit3
__device__ __forceinline__ int wp(int u) { return u ^ ((u >> 3) & 1); }

__device__ __forceinline__ void pack_col(const float* wc, uint4& d0, uint4& d1) {
  d0.x = (unsigned)f2bf(wc[0])  | ((unsigned)f2bf(wc[1])  << 16);
  d0.y = (unsigned)f2bf(wc[2])  | ((unsigned)f2bf(wc[3])  << 16);
  d0.z = (unsigned)f2bf(wc[4])  | ((unsigned)f2bf(wc[5])  << 16);
  d0.w = (unsigned)f2bf(wc[6])  | ((unsigned)f2bf(wc[7])  << 16);
  d1.x = (unsigned)f2bf(wc[8])  | ((unsigned)f2bf(wc[9])  << 16);
  d1.y = (unsigned)f2bf(wc[10]) | ((unsigned)f2bf(wc[11]) << 16);
  d1.z = (unsigned)f2bf(wc[12]) | ((unsigned)f2bf(wc[13]) << 16);
  d1.w = (unsigned)f2bf(wc[14]) | ((unsigned)f2bf(wc[15]) << 16);
}

// MODE 0: load W f32, convert in-kernel, AND write bf16 copies out (pass 0)
// MODE 1: load pre-converted Wbf/ubf (passes 1,2)
// MODE 2: load W f32, convert in-kernel, no writeout (fallback when ws too small)
//
// Block: 1024 threads (16 waves), covers 16 b (one bq) x all 1024 j x NCHUNK n.
// Wave w owns j-tiles jt = w*4+q (q=0..3) -> o = (w*4+q)>>1.
// MFMA swapped: D[j_loc][b_loc] = sum_i W[n][i][j] * u[b][n][i], K=16 of 32 (zero-pad).
// launch_bounds(1024, 8): 8 waves/SIMD -> 2 blocks/CU, VGPR cap 64 (measured use: 40).
template<bool HAS_V, int MODE, int NCHUNK>
__global__ __launch_bounds__(1024, 8)
void pass_kernel(const float* __restrict__ uf, const float* __restrict__ Wf,
                 short* __restrict__ Wbf, short* __restrict__ ubf,
                 const float* __restrict__ vin, float* __restrict__ part)
{
  __shared__ uint4 Wt[2][2048];     // double-buffered W tile (2 x 32KB)
  __shared__ float al[2][32][18];   // logits -> c, [parity][o][b_local]

  const int t  = threadIdx.x;
  const int l  = t & 63;
  const int w  = t >> 6;            // wave 0..15
  const int bid = blockIdx.x;
  const int bq = (bid >> 3) & 3;                    // b quadrant (16 b)
  const int cx = (bid & 7) | ((bid >> 5) << 3);     // chunk (XCD-grouped)
  const int n0 = cx * NCHUNK;

  const int bl = l & 15;            // D col = b_local
  const int b  = bq * 16 + bl;      // global b
  const int h  = l >> 4;            // 0..3: D row group (rows 4h..4h+3)
  const int hA = h & 1;             // k-half (i 0-7 / 8-15) for lanes < 32
  const bool ld = (l < 32);

  // A 16B-unit offsets (within one buffer) per q
  int aoff[4];
  #pragma unroll
  for (int q = 0; q < 4; ++q) {
    int jt = w * 4 + q;
    aoff[q] = wp(2 * (jt * 16 + bl) + hA);
  }

  // v fragments (n-independent): v[b][jt*16 + 4h + r]
  f32x4 vf[4];
  if (HAS_V) {
    #pragma unroll
    for (int q = 0; q < 4; ++q) {
      int jt = w * 4 + q;
      vf[q] = *reinterpret_cast<const f32x4*>(vin + (size_t)b * J + jt * 16 + h * 4);
    }
  }

  f32x4 acc[4];
  #pragma unroll
  for (int q = 0; q < 4; ++q) acc[q] = f32x4{0.f, 0.f, 0.f, 0.f};

  const bool wq = (MODE == 0) && ((t >> 8) == bq);   // this block's Wbf quarter
  const bool uq = (MODE == 0) && (w == 0) && ld;     // wave 0 writes ubf

  // ---- prologue: stage n0 into buf 0; load B-frag for n0 ----
  short8 Bcur = short8{0,0,0,0,0,0,0,0};
  if (MODE == 1) {
    const uint4* src = reinterpret_cast<const uint4*>(Wbf + (size_t)n0 * (D_IN * J));
    Wt[0][t] = src[t];
    Wt[0][t + 1024] = src[t + 1024];
    if (ld)
      Bcur = *reinterpret_cast<const short8*>(ubf + ((size_t)b * N_IN + n0) * D_IN + hA * 8);
  } else {
    float wc[16];
    #pragma unroll
    for (int i = 0; i < 16; ++i) wc[i] = Wf[(size_t)n0 * (D_IN * J) + i * J + t];
    uint4 d0, d1;
    pack_col(wc, d0, d1);
    Wt[0][wp(2 * t)] = d0;
    Wt[0][wp(2 * t + 1)] = d1;
    if (wq) {
      uint4* gdst = reinterpret_cast<uint4*>(Wbf + (size_t)n0 * (D_IN * J));
      gdst[wp(2 * t)] = d0;
      gdst[wp(2 * t + 1)] = d1;
    }
    if (ld) {
      const float* up = uf + ((size_t)b * N_IN + n0) * D_IN + hA * 8;
      float4 a4 = *reinterpret_cast<const float4*>(up);
      float4 b4 = *reinterpret_cast<const float4*>(up + 4);
      Bcur[0] = (short)f2bf(a4.x); Bcur[1] = (short)f2bf(a4.y);
      Bcur[2] = (short)f2bf(a4.z); Bcur[3] = (short)f2bf(a4.w);
      Bcur[4] = (short)f2bf(b4.x); Bcur[5] = (short)f2bf(b4.y);
      Bcur[6] = (short)f2bf(b4.z); Bcur[7] = (short)f2bf(b4.w);
      if (uq)
        *reinterpret_cast<short8*>(ubf + ((size_t)b * N_IN + n0) * D_IN + hA * 8) = Bcur;
    }
  }
  __syncthreads();

  for (int nn = 0; nn < NCHUNK; ++nn) {
    const int n = n0 + nn;
    const int cur = nn & 1, nxt = cur ^ 1;
    const int par = nn & 1;
    const bool more = (nn + 1 < NCHUNK);

    // 1. issue next-tile loads early (write-late below)
    uint4 s0, s1;
    short8 Bn = short8{0,0,0,0,0,0,0,0};
    float wc[16];
    if (more) {
      if (MODE == 1) {
        const uint4* src = reinterpret_cast<const uint4*>(Wbf + (size_t)(n + 1) * (D_IN * J));
        s0 = src[t];
        s1 = src[t + 1024];
        if (ld)
          Bn = *reinterpret_cast<const short8*>(ubf + ((size_t)b * N_IN + n + 1) * D_IN + hA * 8);
      } else {
        #pragma unroll
        for (int i = 0; i < 16; ++i) wc[i] = Wf[(size_t)(n + 1) * (D_IN * J) + i * J + t];
        if (ld) {
          const float* up = uf + ((size_t)b * N_IN + n + 1) * D_IN + hA * 8;
          float4 a4 = *reinterpret_cast<const float4*>(up);
          float4 b4 = *reinterpret_cast<const float4*>(up + 4);
          Bn[0] = (short)f2bf(a4.x); Bn[1] = (short)f2bf(a4.y);
          Bn[2] = (short)f2bf(a4.z); Bn[3] = (short)f2bf(a4.w);
          Bn[4] = (short)f2bf(b4.x); Bn[5] = (short)f2bf(b4.y);
          Bn[6] = (short)f2bf(b4.z); Bn[7] = (short)f2bf(b4.w);
        }
      }
    }

    // 2. uhat tiles via MFMA
    f32x4 C[4];
    const uint4* buf = Wt[cur];
    #pragma unroll
    for (int q = 0; q < 4; ++q) {
      short8 A = short8{0,0,0,0,0,0,0,0};
      if (ld) A = *reinterpret_cast<const short8*>(&buf[aoff[q]]);
      f32x4 z = f32x4{0.f, 0.f, 0.f, 0.f};
      C[q] = __builtin_amdgcn_mfma_f32_16x16x32_bf16(A, Bcur, z, 0, 0, 0);
    }

    if (HAS_V) {
      // 3. agreement a[b][o] = sum_k uhat*v
      float ap[2] = {0.f, 0.f};
      #pragma unroll
      for (int q = 0; q < 4; ++q) {
        float s = C[q][0] * vf[q][0] + C[q][1] * vf[q][1]
                + C[q][2] * vf[q][2] + C[q][3] * vf[q][3];
        ap[q >> 1] += s;
      }
      #pragma unroll
      for (int p = 0; p < 2; ++p) {
        float s = ap[p];
        s += __shfl_xor(s, 16);
        s += __shfl_xor(s, 32);
        if (l < 16) al[par][w * 2 + p][l] = s;
      }

      // 4. write-late staging into other buffer
      if (more) {
        if (MODE == 1) {
          Wt[nxt][t] = s0;
          Wt[nxt][t + 1024] = s1;
        } else {
          uint4 d0, d1;
          pack_col(wc, d0, d1);
          Wt[nxt][wp(2 * t)] = d0;
          Wt[nxt][wp(2 * t + 1)] = d1;
          if (wq) {
            uint4* gdst = reinterpret_cast<uint4*>(Wbf + (size_t)(n + 1) * (D_IN * J));
            gdst[wp(2 * t)] = d0;
            gdst[wp(2 * t + 1)] = d1;
          }
          if (ld && uq)
            *reinterpret_cast<short8*>(ubf + ((size_t)b * N_IN + n + 1) * D_IN + hA * 8) = Bn;
        }
      }

      __syncthreads();   // (B) logits staged
      if (t < 512) {     // softmax over o per b: 32-lane o-groups
        int sb = t >> 5, so = t & 31;
        float x = al[par][so][sb];
        float m = x;
        #pragma unroll
        for (int k = 1; k < 32; k <<= 1) m = fmaxf(m, __shfl_xor(m, k));
        float e = __expf(x - m);
        float sm = e;
        #pragma unroll
        for (int k = 1; k < 32; k <<= 1) sm += __shfl_xor(sm, k);
        al[par][so][sb] = e / sm;
      }
      __syncthreads();   // (C) c ready
      #pragma unroll
      for (int q = 0; q < 4; ++q) {
        float c = al[par][(w * 4 + q) >> 1][bl];
        acc[q] += C[q] * c;
      }
      // no end-of-iter barrier: al is parity-double-buffered and every
      // Wt[buf] write->read / read->write pair is separated by (B)+(C)
    } else {
      #pragma unroll
      for (int q = 0; q < 4; ++q) acc[q] += C[q];

      if (more) {
        if (MODE == 1) {
          Wt[nxt][t] = s0;
          Wt[nxt][t + 1024] = s1;
        } else {
          uint4 d0, d1;
          pack_col(wc, d0, d1);
          Wt[nxt][wp(2 * t)] = d0;
          Wt[nxt][wp(2 * t + 1)] = d1;
          if (wq) {
            uint4* gdst = reinterpret_cast<uint4*>(Wbf + (size_t)(n + 1) * (D_IN * J));
            gdst[wp(2 * t)] = d0;
            gdst[wp(2 * t + 1)] = d1;
          }
          if (ld && uq)
            *reinterpret_cast<short8*>(ubf + ((size_t)b * N_IN + n + 1) * D_IN + hA * 8) = Bn;
        }
      }
      __syncthreads();   // staging barrier (only one per iter in this path)
    }

    Bcur = Bn;
  }

  // epilogue: part[cx][j][b] (transposed -> coalesced b-fast writes)
  #pragma unroll
  for (int q = 0; q < 4; ++q) {
    int jbase = (w * 4 + q) * 16 + h * 4;
    #pragma unroll
    for (int r = 0; r < 4; ++r)
      part[((size_t)cx * J + jbase + r) * 64 + b] = acc[q][r];
  }
}

// Fused chunk-reduce + squash. grid = 32 (one block per o), 1024 threads.
// out[b][o*32+k] = scale(b) * x[b][k] (+ addv), x = prescale * sum_c part[c][j][b]
template<int NC>
__global__ void rsq_kernel(const float* __restrict__ part, const float* __restrict__ addv,
                           float* __restrict__ out, float prescale)
{
  __shared__ float sl[32][65];
  __shared__ float scl[64];
  const int o  = blockIdx.x;
  const int t  = threadIdx.x;
  const int jl = t >> 6;        // 0..15
  const int b  = t & 63;

  #pragma unroll
  for (int half = 0; half < 2; ++half) {
    int k = half * 16 + jl;
    const float* p = part + (size_t)(o * 32 + k) * 64 + b;
    float s = 0.f;
    #pragma unroll 8
    for (int c = 0; c < NC; ++c) s += p[(size_t)c * (J * 64)];
    sl[k][b] = s * prescale;
  }
  __syncthreads();
  if (t < 64) {
    float n2 = 0.f;
    #pragma unroll
    for (int k = 0; k < 32; ++k) { float x = sl[k][t]; n2 += x * x; }
    scl[t] = sqrtf(n2) / (1.f + n2);
  }
  __syncthreads();
  #pragma unroll
  for (int half = 0; half < 2; ++half) {
    int b2 = (t >> 5) + half * 32;
    int k2 = t & 31;
    int idx = b2 * J + o * 32 + k2;
    float val = scl[b2] * sl[k2][b2];
    if (addv) val += addv[idx];
    out[idx] = val;
  }
}

template<int MODE0, int MODE12, int NCHUNK>
static void run_passes(const float* u, const float* W, short* Wbf, short* ubf,
                       float* part, float* v0, float* vs, float* out, hipStream_t stream)
{
  constexpr int NC = N_IN / NCHUNK;
  dim3 grid(4 * NC);
  // r=0: c uniform (pass 0 also emits bf16 W/u when MODE0==0)
  pass_kernel<false, MODE0, NCHUNK><<<grid, 1024, 0, stream>>>(u, W, Wbf, ubf, nullptr, part);
  rsq_kernel<NC><<<32, 1024, 0, stream>>>(part, nullptr, v0, 1.f / 32.f);
  // r=1: logits = uhat.v0 ; vs = v0 + squash(s1)
  pass_kernel<true, MODE12, NCHUNK><<<grid, 1024, 0, stream>>>(u, W, Wbf, ubf, v0, part);
  rsq_kernel<NC><<<32, 1024, 0, stream>>>(part, v0, vs, 1.f);
  // r=2: logits = uhat.(v0+v1) ; out = squash(s2)
  pass_kernel<true, MODE12, NCHUNK><<<grid, 1024, 0, stream>>>(u, W, Wbf, ubf, vs, part);
  rsq_kernel<NC><<<32, 1024, 0, stream>>>(part, nullptr, out, 1.f);
}

extern "C" void kernel_launch(void* const* d_in, const int* in_sizes, int n_in,
                              void* d_out, int out_size, void* d_ws, size_t ws_size,
                              hipStream_t stream)
{
  const float* u = (const float*)d_in[0];
  const float* W = (const float*)d_in[1];
  float* out = (float*)d_out;
  char* ws = (char*)d_ws;

  const size_t WBF_B = (size_t)N_IN * D_IN * J * 2;        // 64 MB
  const size_t UBF_B = (size_t)BATCH * N_IN * D_IN * 2;    // 4 MB
  const size_t SMALL = 2ull * BATCH * J * 4;               // v0+vs

  auto part_bytes = [](int nchunk) { return (size_t)(N_IN / nchunk) * J * 64 * 4; };

  if (ws_size >= WBF_B + UBF_B + part_bytes(16) + SMALL) {
    // preferred: NCHUNK=16 -> grid 512 -> 2 blocks/CU
    short* Wbf = (short*)ws;
    short* ubf = (short*)(ws + WBF_B);
    float* part = (float*)(ws + WBF_B + UBF_B);
    float* v0 = part + (size_t)(N_IN / 16) * J * 64;
    float* vs = v0 + BATCH * J;
    run_passes<0, 1, 16>(u, W, Wbf, ubf, part, v0, vs, out, stream);
  } else if (ws_size >= WBF_B + UBF_B + part_bytes(32) + SMALL) {
    short* Wbf = (short*)ws;
    short* ubf = (short*)(ws + WBF_B);
    float* part = (float*)(ws + WBF_B + UBF_B);
    float* v0 = part + (size_t)(N_IN / 32) * J * 64;
    float* vs = v0 + BATCH * J;
    run_passes<0, 1, 32>(u, W, Wbf, ubf, part, v0, vs, out, stream);
  } else if (ws_size >= part_bytes(16) + SMALL) {
    float* part = (float*)ws;
    float* v0 = part + (size_t)(N_IN / 16) * J * 64;
    float* vs = v0 + BATCH * J;
    run_passes<2, 2, 16>(u, W, nullptr, nullptr, part, v0, vs, out, stream);
  } else {
    float* part = (float*)ws;
    float* v0 = part + (size_t)(N_IN / 128) * J * 64;
    float* vs = v0 + BATCH * J;
    run_passes<2, 2, 128>(u, W, nullptr, nullptr, part, v0, vs, out, stream);
  }
}

// Round 7
// 246.127 us; speedup vs baseline: 1.6491x; 1.6491x over previous
//
#include <hip/hip_runtime.h>
#include <math.h>

#define N_OUT 32
#define D_OUT 32
#define N_IN 2048
#define D_IN 16
#define BATCH 64
#define J 1024           // N_OUT*D_OUT

typedef __attribute__((ext_vector_type(8))) short short8;   // 8 bf16 (4 VGPR)
typedef __attribute__((ext_vector_type(4))) float f32x4;    // MFMA C/D

// f32 -> bf16 RNE
__device__ __forceinline__ unsigned short f2bf(float f) {
  unsigned int x = __float_as_uint(f);
  return (unsigned short)((x + 0x7FFFu + ((x >> 16) & 1u)) >> 16);
}

// 16B-unit swizzle inside one n-tile (2048 units): XOR bit0 with bit3
__device__ __forceinline__ int wp(int u) { return u ^ ((u >> 3) & 1); }

// async global->LDS, 16B per lane (linear LDS dest = wave-uniform base + lane*16)
__device__ __forceinline__ void gll16(const void* g, void* l) {
  __builtin_amdgcn_global_load_lds(
      (const __attribute__((address_space(1))) unsigned int*)g,
      (__attribute__((address_space(3))) unsigned int*)l, 16, 0, 0);
}

__device__ __forceinline__ void pack_col(const float* wc, uint4& d0, uint4& d1) {
  d0.x = (unsigned)f2bf(wc[0])  | ((unsigned)f2bf(wc[1])  << 16);
  d0.y = (unsigned)f2bf(wc[2])  | ((unsigned)f2bf(wc[3])  << 16);
  d0.z = (unsigned)f2bf(wc[4])  | ((unsigned)f2bf(wc[5])  << 16);
  d0.w = (unsigned)f2bf(wc[6])  | ((unsigned)f2bf(wc[7])  << 16);
  d1.x = (unsigned)f2bf(wc[8])  | ((unsigned)f2bf(wc[9])  << 16);
  d1.y = (unsigned)f2bf(wc[10]) | ((unsigned)f2bf(wc[11]) << 16);
  d1.z = (unsigned)f2bf(wc[12]) | ((unsigned)f2bf(wc[13]) << 16);
  d1.w = (unsigned)f2bf(wc[14]) | ((unsigned)f2bf(wc[15]) << 16);
}

// MODE 0: load W f32, convert in-kernel, AND write bf16 copies out (pass 0)
// MODE 1: stream pre-swizzled Wbf via global_load_lds (passes 1,2) -- lean regs
// MODE 2: like MODE 0 without writeout (fallback when ws too small)
//
// Block: 1024 threads (16 waves) = 16 b x 1024 j x NCHUNK n.
// Wave w owns j-tiles jt = w*4+q -> o = (w*4+q)>>1.
// MFMA swapped: D[j_loc][b_loc] = sum_i W[n][i][j] * u[b][n][i], K=16 of 32.
template<bool HAS_V, int MODE, int NCHUNK, int MINW>
__global__ __launch_bounds__(1024, MINW)
void pass_kernel(const float* __restrict__ uf, const float* __restrict__ Wf,
                 short* __restrict__ Wbf, short* __restrict__ ubf,
                 const float* __restrict__ vin, float* __restrict__ part)
{
  __shared__ uint4 Wt[2][2048];     // double-buffered W tile (2 x 32KB)
  __shared__ float al[2][32][18];   // logits -> c, [parity][o][b_local]

  const int t  = threadIdx.x;
  const int l  = t & 63;
  const int w  = t >> 6;            // wave 0..15
  const int bid = blockIdx.x;
  const int bq = (bid >> 3) & 3;                    // b quadrant (16 b)
  const int cx = (bid & 7) | ((bid >> 5) << 3);     // chunk (XCD-grouped)
  const int n0 = cx * NCHUNK;

  const int bl = l & 15;            // D col = b_local
  const int b  = bq * 16 + bl;      // global b
  const int h  = l >> 4;            // 0..3: D rows 4h..4h+3
  const int hA = h & 1;             // k-half (i 0-7 / 8-15) for lanes < 32
  const bool ld = (l < 32);

  if constexpr (MODE == 1) {
    // ================= lean path: fits 64 VGPR -> 2 blocks/CU =================
    unsigned vb[8];                 // v as packed bf16 (n-invariant)
    if (HAS_V) {
      #pragma unroll
      for (int q = 0; q < 4; ++q) {
        f32x4 v4 = *reinterpret_cast<const f32x4*>(vin + (size_t)b * J + (w*4+q)*16 + h*4);
        vb[2*q]   = (unsigned)f2bf(v4[0]) | ((unsigned)f2bf(v4[1]) << 16);
        vb[2*q+1] = (unsigned)f2bf(v4[2]) | ((unsigned)f2bf(v4[3]) << 16);
      }
    }
    f32x4 acc[4];
    #pragma unroll
    for (int q = 0; q < 4; ++q) acc[q] = f32x4{0.f, 0.f, 0.f, 0.f};

    // prologue: async-stage tile n0 into buf 0
    {
      const char* gsrc = (const char*)Wbf + (size_t)n0 * (D_IN * J * 2);
      char* ldst = (char*)&Wt[0][0];
      gll16(gsrc + t * 16, ldst + t * 16);
      gll16(gsrc + (t + 1024) * 16, ldst + (t + 1024) * 16);
    }
    __syncthreads();

    for (int nn = 0; nn < NCHUNK; ++nn) {
      const int n = n0 + nn;
      const int cur = nn & 1, nxt = cur ^ 1, par = nn & 1;

      // B first (so MFMA waits vmcnt(2), leaving the glls in flight)
      short8 B = short8{0,0,0,0,0,0,0,0};
      if (ld) B = *reinterpret_cast<const short8*>(ubf + ((size_t)b * N_IN + n) * D_IN + hA * 8);

      // async-prefetch next tile into other buffer
      if (nn + 1 < NCHUNK) {
        const char* gsrc = (const char*)Wbf + (size_t)(n + 1) * (D_IN * J * 2);
        char* ldst = (char*)&Wt[nxt][0];
        gll16(gsrc + t * 16, ldst + t * 16);
        gll16(gsrc + (t + 1024) * 16, ldst + (t + 1024) * 16);
      }

      // uhat tiles via MFMA
      f32x4 C[4];
      const uint4* buf = Wt[cur];
      #pragma unroll
      for (int q = 0; q < 4; ++q) {
        int jt = w * 4 + q;
        short8 A = short8{0,0,0,0,0,0,0,0};
        if (ld) A = *reinterpret_cast<const short8*>(&buf[wp(2 * (jt * 16 + bl) + hA)]);
        f32x4 z = f32x4{0.f, 0.f, 0.f, 0.f};
        C[q] = __builtin_amdgcn_mfma_f32_16x16x32_bf16(A, B, z, 0, 0, 0);
      }

      if (HAS_V) {
        // agreement a[b][o] = sum_k uhat*v (v unpacked from bf16)
        float ap[2] = {0.f, 0.f};
        #pragma unroll
        for (int q = 0; q < 4; ++q) {
          float v0f = __uint_as_float(vb[2*q] << 16);
          float v1f = __uint_as_float(vb[2*q] & 0xffff0000u);
          float v2f = __uint_as_float(vb[2*q+1] << 16);
          float v3f = __uint_as_float(vb[2*q+1] & 0xffff0000u);
          ap[q >> 1] += C[q][0]*v0f + C[q][1]*v1f + C[q][2]*v2f + C[q][3]*v3f;
        }
        #pragma unroll
        for (int p = 0; p < 2; ++p) {
          float s = ap[p];
          s += __shfl_xor(s, 16);
          s += __shfl_xor(s, 32);
          if (l < 16) al[par][w * 2 + p][l] = s;
        }
        __syncthreads();   // (B) logits staged (also drains glls)
        if (t < 512) {     // softmax over o per b: 32-lane o-groups
          int sb = t >> 5, so = t & 31;
          float x = al[par][so][sb];
          float m = x;
          #pragma unroll
          for (int k = 1; k < 32; k <<= 1) m = fmaxf(m, __shfl_xor(m, k));
          float e = __expf(x - m);
          float sm = e;
          #pragma unroll
          for (int k = 1; k < 32; k <<= 1) sm += __shfl_xor(sm, k);
          al[par][so][sb] = e / sm;
        }
        __syncthreads();   // (C) c ready
        #pragma unroll
        for (int q = 0; q < 4; ++q) {
          float c = al[par][(w * 4 + q) >> 1][bl];
          acc[q] += C[q] * c;
        }
        // no end barrier: al parity-buffered; Wt hazards separated by (B)+(C)
      } else {
        #pragma unroll
        for (int q = 0; q < 4; ++q) acc[q] += C[q];
        __syncthreads();   // orders Wt reads vs next iter's gll
      }
    }

    #pragma unroll
    for (int q = 0; q < 4; ++q) {
      int jbase = (w * 4 + q) * 16 + h * 4;
      #pragma unroll
      for (int r = 0; r < 4; ++r)
        part[((size_t)cx * J + jbase + r) * 64 + b] = acc[q][r];
    }
  } else {
    // ================= MODE 0/2: f32-load + convert path (1 block/CU) =================
    f32x4 vf[4];
    if (HAS_V) {
      #pragma unroll
      for (int q = 0; q < 4; ++q)
        vf[q] = *reinterpret_cast<const f32x4*>(vin + (size_t)b * J + (w*4+q)*16 + h*4);
    }
    int aoff[4];
    #pragma unroll
    for (int q = 0; q < 4; ++q) aoff[q] = wp(2 * ((w*4+q) * 16 + bl) + hA);

    f32x4 acc[4];
    #pragma unroll
    for (int q = 0; q < 4; ++q) acc[q] = f32x4{0.f, 0.f, 0.f, 0.f};

    const bool wq = (MODE == 0) && ((t >> 8) == bq);   // this block's Wbf quarter
    const bool uq = (MODE == 0) && (w == 0) && ld;     // wave 0 writes ubf

    short8 Bcur = short8{0,0,0,0,0,0,0,0};
    {
      float wc[16];
      #pragma unroll
      for (int i = 0; i < 16; ++i) wc[i] = Wf[(size_t)n0 * (D_IN * J) + i * J + t];
      uint4 d0, d1;
      pack_col(wc, d0, d1);
      Wt[0][wp(2 * t)] = d0;
      Wt[0][wp(2 * t + 1)] = d1;
      if (wq) {
        uint4* gdst = reinterpret_cast<uint4*>(Wbf + (size_t)n0 * (D_IN * J));
        gdst[wp(2 * t)] = d0;
        gdst[wp(2 * t + 1)] = d1;
      }
      if (ld) {
        const float* up = uf + ((size_t)b * N_IN + n0) * D_IN + hA * 8;
        float4 a4 = *reinterpret_cast<const float4*>(up);
        float4 b4 = *reinterpret_cast<const float4*>(up + 4);
        Bcur[0] = (short)f2bf(a4.x); Bcur[1] = (short)f2bf(a4.y);
        Bcur[2] = (short)f2bf(a4.z); Bcur[3] = (short)f2bf(a4.w);
        Bcur[4] = (short)f2bf(b4.x); Bcur[5] = (short)f2bf(b4.y);
        Bcur[6] = (short)f2bf(b4.z); Bcur[7] = (short)f2bf(b4.w);
        if (uq)
          *reinterpret_cast<short8*>(ubf + ((size_t)b * N_IN + n0) * D_IN + hA * 8) = Bcur;
      }
    }
    __syncthreads();

    for (int nn = 0; nn < NCHUNK; ++nn) {
      const int n = n0 + nn;
      const int cur = nn & 1, nxt = cur ^ 1, par = nn & 1;
      const bool more = (nn + 1 < NCHUNK);

      short8 Bn = short8{0,0,0,0,0,0,0,0};
      float wc[16];
      if (more) {
        #pragma unroll
        for (int i = 0; i < 16; ++i) wc[i] = Wf[(size_t)(n + 1) * (D_IN * J) + i * J + t];
        if (ld) {
          const float* up = uf + ((size_t)b * N_IN + n + 1) * D_IN + hA * 8;
          float4 a4 = *reinterpret_cast<const float4*>(up);
          float4 b4 = *reinterpret_cast<const float4*>(up + 4);
          Bn[0] = (short)f2bf(a4.x); Bn[1] = (short)f2bf(a4.y);
          Bn[2] = (short)f2bf(a4.z); Bn[3] = (short)f2bf(a4.w);
          Bn[4] = (short)f2bf(b4.x); Bn[5] = (short)f2bf(b4.y);
          Bn[6] = (short)f2bf(b4.z); Bn[7] = (short)f2bf(b4.w);
        }
      }

      f32x4 C[4];
      const uint4* buf = Wt[cur];
      #pragma unroll
      for (int q = 0; q < 4; ++q) {
        short8 A = short8{0,0,0,0,0,0,0,0};
        if (ld) A = *reinterpret_cast<const short8*>(&buf[aoff[q]]);
        f32x4 z = f32x4{0.f, 0.f, 0.f, 0.f};
        C[q] = __builtin_amdgcn_mfma_f32_16x16x32_bf16(A, Bcur, z, 0, 0, 0);
      }

      if (HAS_V) {
        float ap[2] = {0.f, 0.f};
        #pragma unroll
        for (int q = 0; q < 4; ++q) {
          float s = C[q][0]*vf[q][0] + C[q][1]*vf[q][1] + C[q][2]*vf[q][2] + C[q][3]*vf[q][3];
          ap[q >> 1] += s;
        }
        #pragma unroll
        for (int p = 0; p < 2; ++p) {
          float s = ap[p];
          s += __shfl_xor(s, 16);
          s += __shfl_xor(s, 32);
          if (l < 16) al[par][w * 2 + p][l] = s;
        }
        if (more) {
          uint4 d0, d1;
          pack_col(wc, d0, d1);
          Wt[nxt][wp(2 * t)] = d0;
          Wt[nxt][wp(2 * t + 1)] = d1;
          if (wq) {
            uint4* gdst = reinterpret_cast<uint4*>(Wbf + (size_t)(n + 1) * (D_IN * J));
            gdst[wp(2 * t)] = d0;
            gdst[wp(2 * t + 1)] = d1;
          }
          if (ld && uq)
            *reinterpret_cast<short8*>(ubf + ((size_t)b * N_IN + n + 1) * D_IN + hA * 8) = Bn;
        }
        __syncthreads();   // (B)
        if (t < 512) {
          int sb = t >> 5, so = t & 31;
          float x = al[par][so][sb];
          float m = x;
          #pragma unroll
          for (int k = 1; k < 32; k <<= 1) m = fmaxf(m, __shfl_xor(m, k));
          float e = __expf(x - m);
          float sm = e;
          #pragma unroll
          for (int k = 1; k < 32; k <<= 1) sm += __shfl_xor(sm, k);
          al[par][so][sb] = e / sm;
        }
        __syncthreads();   // (C)
        #pragma unroll
        for (int q = 0; q < 4; ++q) {
          float c = al[par][(w * 4 + q) >> 1][bl];
          acc[q] += C[q] * c;
        }
      } else {
        #pragma unroll
        for (int q = 0; q < 4; ++q) acc[q] += C[q];
        if (more) {
          uint4 d0, d1;
          pack_col(wc, d0, d1);
          Wt[nxt][wp(2 * t)] = d0;
          Wt[nxt][wp(2 * t + 1)] = d1;
          if (wq) {
            uint4* gdst = reinterpret_cast<uint4*>(Wbf + (size_t)(n + 1) * (D_IN * J));
            gdst[wp(2 * t)] = d0;
            gdst[wp(2 * t + 1)] = d1;
          }
          if (ld && uq)
            *reinterpret_cast<short8*>(ubf + ((size_t)b * N_IN + n + 1) * D_IN + hA * 8) = Bn;
        }
        __syncthreads();
      }
      Bcur = Bn;
    }

    #pragma unroll
    for (int q = 0; q < 4; ++q) {
      int jbase = (w * 4 + q) * 16 + h * 4;
      #pragma unroll
      for (int r = 0; r < 4; ++r)
        part[((size_t)cx * J + jbase + r) * 64 + b] = acc[q][r];
    }
  }
}

// Fused chunk-reduce + squash. grid = 128 (o x b-quadrant), 1024 threads.
template<int NC>
__global__ __launch_bounds__(1024)
void rsq_kernel(const float* __restrict__ part, const float* __restrict__ addv,
                float* __restrict__ out, float prescale)
{
  __shared__ float ps[2][32][17];
  __shared__ float vl[32][17];
  __shared__ float scl[16];
  const int o  = blockIdx.x >> 2;
  const int bq = blockIdx.x & 3;
  const int t  = threadIdx.x;
  {
    const int bb = t & 15;
    const int kk = (t >> 4) & 31;
    const int ch = t >> 9;         // 0/1
    const float* p = part + (size_t)(o * 32 + kk) * 64 + bq * 16 + bb;
    float s = 0.f;
    #pragma unroll 8
    for (int c = ch * (NC / 2); c < (ch + 1) * (NC / 2); ++c)
      s += p[(size_t)c * (J * 64)];
    ps[ch][kk][bb] = s;
  }
  __syncthreads();
  if (t < 512) {
    int kk = t >> 4, bb = t & 15;
    vl[kk][bb] = (ps[0][kk][bb] + ps[1][kk][bb]) * prescale;
  }
  __syncthreads();
  if (t < 16) {
    float n2 = 0.f;
    #pragma unroll
    for (int k = 0; k < 32; ++k) { float x = vl[k][t]; n2 += x * x; }
    scl[t] = sqrtf(n2) / (1.f + n2);
  }
  __syncthreads();
  if (t < 512) {
    int bb = t >> 5, kk = t & 31;
    int idx = (bq * 16 + bb) * J + o * 32 + kk;
    float val = scl[bb] * vl[kk][bb];
    if (addv) val += addv[idx];
    out[idx] = val;
  }
}

extern "C" void kernel_launch(void* const* d_in, const int* in_sizes, int n_in,
                              void* d_out, int out_size, void* d_ws, size_t ws_size,
                              hipStream_t stream)
{
  const float* u = (const float*)d_in[0];
  const float* W = (const float*)d_in[1];
  float* out = (float*)d_out;
  char* ws = (char*)d_ws;

  const size_t WBF_B = (size_t)N_IN * D_IN * J * 2;        // 64 MB
  const size_t UBF_B = (size_t)BATCH * N_IN * D_IN * 2;    // 4 MB
  const size_t SMALL = 2ull * BATCH * J * 4;               // v0+vs

  if (ws_size >= WBF_B + UBF_B + (size_t)128 * J * 64 * 4 + SMALL) {
    short* Wbf = (short*)ws;
    short* ubf = (short*)(ws + WBF_B);
    float* part = (float*)(ws + WBF_B + UBF_B);
    float* v0 = part + (size_t)128 * J * 64;
    float* vs = v0 + BATCH * J;
    // r=0: pass0 converts + emits Wbf/ubf; NCHUNK=32 -> 64 chunks, 1 block/CU
    pass_kernel<false, 0, 32, 4><<<256, 1024, 0, stream>>>(u, W, Wbf, ubf, nullptr, part);
    rsq_kernel<64><<<128, 1024, 0, stream>>>(part, nullptr, v0, 1.f / 32.f);
    // r=1,2: lean MODE1, NCHUNK=16 -> 128 chunks, 2 blocks/CU
    pass_kernel<true, 1, 16, 8><<<512, 1024, 0, stream>>>(u, W, Wbf, ubf, v0, part);
    rsq_kernel<128><<<128, 1024, 0, stream>>>(part, v0, vs, 1.f);
    pass_kernel<true, 1, 16, 8><<<512, 1024, 0, stream>>>(u, W, Wbf, ubf, vs, part);
    rsq_kernel<128><<<128, 1024, 0, stream>>>(part, nullptr, out, 1.f);
  } else if (ws_size >= (size_t)64 * J * 64 * 4 + SMALL) {
    float* part = (float*)ws;
    float* v0 = part + (size_t)64 * J * 64;
    float* vs = v0 + BATCH * J;
    pass_kernel<false, 2, 32, 4><<<256, 1024, 0, stream>>>(u, W, nullptr, nullptr, nullptr, part);
    rsq_kernel<64><<<128, 1024, 0, stream>>>(part, nullptr, v0, 1.f / 32.f);
    pass_kernel<true, 2, 32, 4><<<256, 1024, 0, stream>>>(u, W, nullptr, nullptr, v0, part);
    rsq_kernel<64><<<128, 1024, 0, stream>>>(part, v0, vs, 1.f);
    pass_kernel<true, 2, 32, 4><<<256, 1024, 0, stream>>>(u, W, nullptr, nullptr, vs, part);
    rsq_kernel<64><<<128, 1024, 0, stream>>>(part, nullptr, out, 1.f);
  } else {
    float* part = (float*)ws;
    float* v0 = part + (size_t)16 * J * 64;
    float* vs = v0 + BATCH * J;
    pass_kernel<false, 2, 128, 4><<<64, 1024, 0, stream>>>(u, W, nullptr, nullptr, nullptr, part);
    rsq_kernel<16><<<128, 1024, 0, stream>>>(part, nullptr, v0, 1.f / 32.f);
    pass_kernel<true, 2, 128, 4><<<64, 1024, 0, stream>>>(u, W, nullptr, nullptr, v0, part);
    rsq_kernel<16><<<128, 1024, 0, stream>>>(part, v0, vs, 1.f);
    pass_kernel<true, 2, 128, 4><<<64, 1024, 0, stream>>>(u, W, nullptr, nullptr, vs, part);
    rsq_kernel<16><<<128, 1024, 0, stream>>>(part, nullptr, out, 1.f);
  }
}

// Round 8
// 189.478 us; speedup vs baseline: 2.1422x; 1.2990x over previous
//
#include <hip/hip_runtime.h>
#include <math.h>

#define N_OUT 32
#define D_OUT 32
#define N_IN 2048
#define D_IN 16
#define BATCH 64
#define J 1024           // N_OUT*D_OUT

typedef __attribute__((ext_vector_type(8))) short short8;   // 8 bf16 (4 VGPR)
typedef __attribute__((ext_vector_type(4))) float f32x4;    // MFMA C/D

// f32 -> bf16 RNE
__device__ __forceinline__ unsigned short f2bf(float f) {
  unsigned int x = __float_as_uint(f);
  return (unsigned short)((x + 0x7FFFu + ((x >> 16) & 1u)) >> 16);
}

// 16B-unit swizzle inside one n-tile (2048 units): XOR bit0 with bit3
__device__ __forceinline__ int wp(int u) { return u ^ ((u >> 3) & 1); }

__device__ __forceinline__ void pack_col(const float* wc, uint4& d0, uint4& d1) {
  d0.x = (unsigned)f2bf(wc[0])  | ((unsigned)f2bf(wc[1])  << 16);
  d0.y = (unsigned)f2bf(wc[2])  | ((unsigned)f2bf(wc[3])  << 16);
  d0.z = (unsigned)f2bf(wc[4])  | ((unsigned)f2bf(wc[5])  << 16);
  d0.w = (unsigned)f2bf(wc[6])  | ((unsigned)f2bf(wc[7])  << 16);
  d1.x = (unsigned)f2bf(wc[8])  | ((unsigned)f2bf(wc[9])  << 16);
  d1.y = (unsigned)f2bf(wc[10]) | ((unsigned)f2bf(wc[11]) << 16);
  d1.z = (unsigned)f2bf(wc[12]) | ((unsigned)f2bf(wc[13]) << 16);
  d1.w = (unsigned)f2bf(wc[14]) | ((unsigned)f2bf(wc[15]) << 16);
}

// MODE 0: load W f32, convert in-kernel, AND write bf16 copies out (pass 0)
// MODE 1: reg-staged pre-converted Wbf/ubf (passes 1,2) -- round-5 proven path
// MODE 2: like MODE 0 without writeout (fallback when ws too small)
//
// Block: 1024 threads (16 waves) = 16 b x 1024 j x NCHUNK n.
// Wave w owns j-tiles jt = w*4+q -> o = (w*4+q)>>1.
// MFMA swapped: D[j_loc][b_loc] = sum_i W[n][i][j] * u[b][n][i], K=16 of 32.
template<bool HAS_V, int MODE, int NCHUNK, int MINW>
__global__ __launch_bounds__(1024, MINW)
void pass_kernel(const float* __restrict__ uf, const float* __restrict__ Wf,
                 short* __restrict__ Wbf, short* __restrict__ ubf,
                 const float* __restrict__ vin, float* __restrict__ part)
{
  __shared__ uint4 Wt[2][2048];     // double-buffered W tile (2 x 32KB)
  __shared__ float al[2][32][18];   // logits -> c, [parity][o][b_local]

  const int t  = threadIdx.x;
  const int l  = t & 63;
  const int w  = t >> 6;            // wave 0..15
  const int bid = blockIdx.x;
  const int bq = (bid >> 3) & 3;                    // b quadrant (16 b)
  const int cx = (bid & 7) | ((bid >> 5) << 3);     // chunk (XCD-grouped)
  const int n0 = cx * NCHUNK;

  const int bl = l & 15;            // D col = b_local
  const int b  = bq * 16 + bl;      // global b
  const int h  = l >> 4;            // 0..3: D rows 4h..4h+3
  const int hA = h & 1;             // k-half (i 0-7 / 8-15) for lanes < 32
  const bool ld = (l < 32);

  // v fragments (n-invariant): v[b][jt*16 + 4h + r]
  f32x4 vf[4];
  if (HAS_V) {
    #pragma unroll
    for (int q = 0; q < 4; ++q)
      vf[q] = *reinterpret_cast<const f32x4*>(vin + (size_t)b * J + (w*4+q)*16 + h*4);
  }

  int aoff[4];
  #pragma unroll
  for (int q = 0; q < 4; ++q) aoff[q] = wp(2 * ((w*4+q) * 16 + bl) + hA);

  f32x4 acc[4];
  #pragma unroll
  for (int q = 0; q < 4; ++q) acc[q] = f32x4{0.f, 0.f, 0.f, 0.f};

  if constexpr (MODE == 1) {
    // ============ MODE 1: reg-staged bf16 tiles (round-5 proven) ============
    short8 Bcur = short8{0,0,0,0,0,0,0,0};
    {
      const uint4* src = reinterpret_cast<const uint4*>(Wbf + (size_t)n0 * (D_IN * J));
      Wt[0][t] = src[t];
      Wt[0][t + 1024] = src[t + 1024];
      if (ld)
        Bcur = *reinterpret_cast<const short8*>(ubf + ((size_t)b * N_IN + n0) * D_IN + hA * 8);
    }
    __syncthreads();

    for (int nn = 0; nn < NCHUNK; ++nn) {
      const int n = n0 + nn;
      const int cur = nn & 1, nxt = cur ^ 1, par = nn & 1;
      const bool more = (nn + 1 < NCHUNK);

      // 1. issue next-tile loads early (write-late below)
      uint4 s0, s1;
      short8 Bn = short8{0,0,0,0,0,0,0,0};
      if (more) {
        const uint4* src = reinterpret_cast<const uint4*>(Wbf + (size_t)(n + 1) * (D_IN * J));
        s0 = src[t];
        s1 = src[t + 1024];
        if (ld)
          Bn = *reinterpret_cast<const short8*>(ubf + ((size_t)b * N_IN + n + 1) * D_IN + hA * 8);
      }

      // 2. uhat tiles via MFMA
      f32x4 C[4];
      const uint4* buf = Wt[cur];
      #pragma unroll
      for (int q = 0; q < 4; ++q) {
        short8 A = short8{0,0,0,0,0,0,0,0};
        if (ld) A = *reinterpret_cast<const short8*>(&buf[aoff[q]]);
        f32x4 z = f32x4{0.f, 0.f, 0.f, 0.f};
        C[q] = __builtin_amdgcn_mfma_f32_16x16x32_bf16(A, Bcur, z, 0, 0, 0);
      }

      // 3. agreement a[b][o] = sum_k uhat*v
      {
        float ap[2] = {0.f, 0.f};
        #pragma unroll
        for (int q = 0; q < 4; ++q) {
          float s = C[q][0]*vf[q][0] + C[q][1]*vf[q][1] + C[q][2]*vf[q][2] + C[q][3]*vf[q][3];
          ap[q >> 1] += s;
        }
        #pragma unroll
        for (int p = 0; p < 2; ++p) {
          float s = ap[p];
          s += __shfl_xor(s, 16);
          s += __shfl_xor(s, 32);
          if (l < 16) al[par][w * 2 + p][l] = s;
        }
      }

      // 4. write-late staging into other buffer
      if (more) {
        Wt[nxt][t] = s0;
        Wt[nxt][t + 1024] = s1;
      }

      __syncthreads();   // (B) logits staged
      if (t < 512) {     // softmax over o per b: 32-lane o-groups
        int sb = t >> 5, so = t & 31;
        float x = al[par][so][sb];
        float m = x;
        #pragma unroll
        for (int k = 1; k < 32; k <<= 1) m = fmaxf(m, __shfl_xor(m, k));
        float e = __expf(x - m);
        float sm = e;
        #pragma unroll
        for (int k = 1; k < 32; k <<= 1) sm += __shfl_xor(sm, k);
        al[par][so][sb] = e / sm;
      }
      __syncthreads();   // (C) c ready
      #pragma unroll
      for (int q = 0; q < 4; ++q) {
        float c = al[par][(w * 4 + q) >> 1][bl];
        acc[q] += C[q] * c;
      }
      // no end barrier: al parity-buffered; Wt read->overwrite separated by (B)
      Bcur = Bn;
    }
  } else {
    // ============ MODE 0/2: f32 load + convert, MLP-forced ============
    const bool wq = (MODE == 0) && ((t >> 8) == bq);   // this block's Wbf quarter
    const bool uq = (MODE == 0) && (w == 0) && ld;     // wave 0 writes ubf

    short8 Bcur = short8{0,0,0,0,0,0,0,0};
    {
      float wc[16];
      const float* wsrc = Wf + (size_t)n0 * (D_IN * J) + t;
      #pragma unroll
      for (int i = 0; i < 16; ++i) wc[i] = wsrc[i * J];
      float4 a4 = {0,0,0,0}, b4 = {0,0,0,0};
      if (ld) {
        const float* up = uf + ((size_t)b * N_IN + n0) * D_IN + hA * 8;
        a4 = *reinterpret_cast<const float4*>(up);
        b4 = *reinterpret_cast<const float4*>(up + 4);
      }
      __builtin_amdgcn_sched_barrier(0);   // all loads issued before packing
      uint4 d0, d1;
      pack_col(wc, d0, d1);
      Wt[0][wp(2 * t)] = d0;
      Wt[0][wp(2 * t + 1)] = d1;
      if (wq) {
        uint4* gdst = reinterpret_cast<uint4*>(Wbf + (size_t)n0 * (D_IN * J));
        gdst[wp(2 * t)] = d0;
        gdst[wp(2 * t + 1)] = d1;
      }
      if (ld) {
        Bcur[0] = (short)f2bf(a4.x); Bcur[1] = (short)f2bf(a4.y);
        Bcur[2] = (short)f2bf(a4.z); Bcur[3] = (short)f2bf(a4.w);
        Bcur[4] = (short)f2bf(b4.x); Bcur[5] = (short)f2bf(b4.y);
        Bcur[6] = (short)f2bf(b4.z); Bcur[7] = (short)f2bf(b4.w);
        if (uq)
          *reinterpret_cast<short8*>(ubf + ((size_t)b * N_IN + n0) * D_IN + hA * 8) = Bcur;
      }
    }
    __syncthreads();

    for (int nn = 0; nn < NCHUNK; ++nn) {
      const int n = n0 + nn;
      const int cur = nn & 1, nxt = cur ^ 1, par = nn & 1;
      const bool more = (nn + 1 < NCHUNK);

      // 1. issue ALL next-tile loads, then fence the scheduler so nothing
      //    (packing, MFMA addr calc) gets interleaved above them.
      float wc[16];
      float4 a4 = {0,0,0,0}, b4 = {0,0,0,0};
      if (more) {
        const float* wsrc = Wf + (size_t)(n + 1) * (D_IN * J) + t;
        #pragma unroll
        for (int i = 0; i < 16; ++i) wc[i] = wsrc[i * J];
        if (ld) {
          const float* up = uf + ((size_t)b * N_IN + n + 1) * D_IN + hA * 8;
          a4 = *reinterpret_cast<const float4*>(up);
          b4 = *reinterpret_cast<const float4*>(up + 4);
        }
        __builtin_amdgcn_sched_barrier(0);
      }

      // 2. uhat tiles via MFMA
      f32x4 C[4];
      const uint4* buf = Wt[cur];
      #pragma unroll
      for (int q = 0; q < 4; ++q) {
        short8 A = short8{0,0,0,0,0,0,0,0};
        if (ld) A = *reinterpret_cast<const short8*>(&buf[aoff[q]]);
        f32x4 z = f32x4{0.f, 0.f, 0.f, 0.f};
        C[q] = __builtin_amdgcn_mfma_f32_16x16x32_bf16(A, Bcur, z, 0, 0, 0);
      }

      short8 Bn = short8{0,0,0,0,0,0,0,0};
      if (more && ld) {
        Bn[0] = (short)f2bf(a4.x); Bn[1] = (short)f2bf(a4.y);
        Bn[2] = (short)f2bf(a4.z); Bn[3] = (short)f2bf(a4.w);
        Bn[4] = (short)f2bf(b4.x); Bn[5] = (short)f2bf(b4.y);
        Bn[6] = (short)f2bf(b4.z); Bn[7] = (short)f2bf(b4.w);
      }

      if (HAS_V) {
        float ap[2] = {0.f, 0.f};
        #pragma unroll
        for (int q = 0; q < 4; ++q) {
          float s = C[q][0]*vf[q][0] + C[q][1]*vf[q][1] + C[q][2]*vf[q][2] + C[q][3]*vf[q][3];
          ap[q >> 1] += s;
        }
        #pragma unroll
        for (int p = 0; p < 2; ++p) {
          float s = ap[p];
          s += __shfl_xor(s, 16);
          s += __shfl_xor(s, 32);
          if (l < 16) al[par][w * 2 + p][l] = s;
        }
        if (more) {
          uint4 d0, d1;
          pack_col(wc, d0, d1);
          Wt[nxt][wp(2 * t)] = d0;
          Wt[nxt][wp(2 * t + 1)] = d1;
          if (wq) {
            uint4* gdst = reinterpret_cast<uint4*>(Wbf + (size_t)(n + 1) * (D_IN * J));
            gdst[wp(2 * t)] = d0;
            gdst[wp(2 * t + 1)] = d1;
          }
          if (ld && uq)
            *reinterpret_cast<short8*>(ubf + ((size_t)b * N_IN + n + 1) * D_IN + hA * 8) = Bn;
        }
        __syncthreads();   // (B)
        if (t < 512) {
          int sb = t >> 5, so = t & 31;
          float x = al[par][so][sb];
          float m = x;
          #pragma unroll
          for (int k = 1; k < 32; k <<= 1) m = fmaxf(m, __shfl_xor(m, k));
          float e = __expf(x - m);
          float sm = e;
          #pragma unroll
          for (int k = 1; k < 32; k <<= 1) sm += __shfl_xor(sm, k);
          al[par][so][sb] = e / sm;
        }
        __syncthreads();   // (C)
        #pragma unroll
        for (int q = 0; q < 4; ++q) {
          float c = al[par][(w * 4 + q) >> 1][bl];
          acc[q] += C[q] * c;
        }
      } else {
        #pragma unroll
        for (int q = 0; q < 4; ++q) acc[q] += C[q];
        if (more) {
          uint4 d0, d1;
          pack_col(wc, d0, d1);
          Wt[nxt][wp(2 * t)] = d0;
          Wt[nxt][wp(2 * t + 1)] = d1;
          if (wq) {
            uint4* gdst = reinterpret_cast<uint4*>(Wbf + (size_t)(n + 1) * (D_IN * J));
            gdst[wp(2 * t)] = d0;
            gdst[wp(2 * t + 1)] = d1;
          }
          if (ld && uq)
            *reinterpret_cast<short8*>(ubf + ((size_t)b * N_IN + n + 1) * D_IN + hA * 8) = Bn;
        }
        __syncthreads();
      }
      Bcur = Bn;
    }
  }

  // epilogue: part[cx][j][b] (transposed -> coalesced b-fast writes)
  #pragma unroll
  for (int q = 0; q < 4; ++q) {
    int jbase = (w * 4 + q) * 16 + h * 4;
    #pragma unroll
    for (int r = 0; r < 4; ++r)
      part[((size_t)cx * J + jbase + r) * 64 + b] = acc[q][r];
  }
}

// Fused chunk-reduce + squash. grid = 128 (o x b-quadrant), 1024 threads.
template<int NC>
__global__ __launch_bounds__(1024)
void rsq_kernel(const float* __restrict__ part, const float* __restrict__ addv,
                float* __restrict__ out, float prescale)
{
  __shared__ float ps[2][32][17];
  __shared__ float vl[32][17];
  __shared__ float scl[16];
  const int o  = blockIdx.x >> 2;
  const int bq = blockIdx.x & 3;
  const int t  = threadIdx.x;
  {
    const int bb = t & 15;
    const int kk = (t >> 4) & 31;
    const int ch = t >> 9;         // 0/1
    const float* p = part + (size_t)(o * 32 + kk) * 64 + bq * 16 + bb;
    float s = 0.f;
    #pragma unroll 8
    for (int c = ch * (NC / 2); c < (ch + 1) * (NC / 2); ++c)
      s += p[(size_t)c * (J * 64)];
    ps[ch][kk][bb] = s;
  }
  __syncthreads();
  if (t < 512) {
    int kk = t >> 4, bb = t & 15;
    vl[kk][bb] = (ps[0][kk][bb] + ps[1][kk][bb]) * prescale;
  }
  __syncthreads();
  if (t < 16) {
    float n2 = 0.f;
    #pragma unroll
    for (int k = 0; k < 32; ++k) { float x = vl[k][t]; n2 += x * x; }
    scl[t] = sqrtf(n2) / (1.f + n2);
  }
  __syncthreads();
  if (t < 512) {
    int bb = t >> 5, kk = t & 31;
    int idx = (bq * 16 + bb) * J + o * 32 + kk;
    float val = scl[bb] * vl[kk][bb];
    if (addv) val += addv[idx];
    out[idx] = val;
  }
}

extern "C" void kernel_launch(void* const* d_in, const int* in_sizes, int n_in,
                              void* d_out, int out_size, void* d_ws, size_t ws_size,
                              hipStream_t stream)
{
  const float* u = (const float*)d_in[0];
  const float* W = (const float*)d_in[1];
  float* out = (float*)d_out;
  char* ws = (char*)d_ws;

  const size_t WBF_B = (size_t)N_IN * D_IN * J * 2;        // 64 MB
  const size_t UBF_B = (size_t)BATCH * N_IN * D_IN * 2;    // 4 MB
  const size_t SMALL = 2ull * BATCH * J * 4;               // v0+vs
  const size_t PART64 = (size_t)64 * J * 64 * 4;           // 16.7 MB (NC=64)

  if (ws_size >= WBF_B + UBF_B + PART64 + SMALL) {
    short* Wbf = (short*)ws;
    short* ubf = (short*)(ws + WBF_B);
    float* part = (float*)(ws + WBF_B + UBF_B);
    float* v0 = part + (size_t)64 * J * 64;
    float* vs = v0 + BATCH * J;
    // r=0: pass0 converts + emits Wbf/ubf (MLP-forced loads)
    pass_kernel<false, 0, 32, 1><<<256, 1024, 0, stream>>>(u, W, Wbf, ubf, nullptr, part);
    rsq_kernel<64><<<128, 1024, 0, stream>>>(part, nullptr, v0, 1.f / 32.f);
    // r=1,2: round-5 proven reg-staged MODE1
    pass_kernel<true, 1, 32, 1><<<256, 1024, 0, stream>>>(u, W, Wbf, ubf, v0, part);
    rsq_kernel<64><<<128, 1024, 0, stream>>>(part, v0, vs, 1.f);
    pass_kernel<true, 1, 32, 1><<<256, 1024, 0, stream>>>(u, W, Wbf, ubf, vs, part);
    rsq_kernel<64><<<128, 1024, 0, stream>>>(part, nullptr, out, 1.f);
  } else if (ws_size >= PART64 + SMALL) {
    float* part = (float*)ws;
    float* v0 = part + (size_t)64 * J * 64;
    float* vs = v0 + BATCH * J;
    pass_kernel<false, 2, 32, 1><<<256, 1024, 0, stream>>>(u, W, nullptr, nullptr, nullptr, part);
    rsq_kernel<64><<<128, 1024, 0, stream>>>(part, nullptr, v0, 1.f / 32.f);
    pass_kernel<true, 2, 32, 1><<<256, 1024, 0, stream>>>(u, W, nullptr, nullptr, v0, part);
    rsq_kernel<64><<<128, 1024, 0, stream>>>(part, v0, vs, 1.f);
    pass_kernel<true, 2, 32, 1><<<256, 1024, 0, stream>>>(u, W, nullptr, nullptr, vs, part);
    rsq_kernel<64><<<128, 1024, 0, stream>>>(part, nullptr, out, 1.f);
  } else {
    float* part = (float*)ws;
    float* v0 = part + (size_t)16 * J * 64;
    float* vs = v0 + BATCH * J;
    pass_kernel<false, 2, 128, 1><<<64, 1024, 0, stream>>>(u, W, nullptr, nullptr, nullptr, part);
    rsq_kernel<16><<<128, 1024, 0, stream>>>(part, nullptr, v0, 1.f / 32.f);
    pass_kernel<true, 2, 128, 1><<<64, 1024, 0, stream>>>(u, W, nullptr, nullptr, v0, part);
    rsq_kernel<16><<<128, 1024, 0, stream>>>(part, v0, vs, 1.f);
    pass_kernel<true, 2, 128, 1><<<64, 1024, 0, stream>>>(u, W, nullptr, nullptr, vs, part);
    rsq_kernel<16><<<128, 1024, 0, stream>>>(part, nullptr, out, 1.f);
  }
}